// Round 1
// baseline (1094.616 us; speedup 1.0000x reference)
//
#include <hip/hip_runtime.h>

#define NN 100000
#define NE 1600000
#define BN_EPS 1e-5f

// ---- workspace layout (bytes) ----
static constexpr size_t OFF_ROW  = 0;              // (NN+1) ints : CSR row offsets
static constexpr size_t OFF_CNT  = 512u*1024;      // NN ints     : per-node in-degree
static constexpr size_t OFF_CUR  = 1024u*1024;     // NN ints     : fill cursors
static constexpr size_t OFF_PART = 1536u*1024;     // 256 ints    : scan partials
static constexpr size_t OFF_CSR  = 1600u*1024;     // NE ints     : CSR src indices
static constexpr size_t OFF_Y0   = 8u*1024*1024;   // NN*64 f32
static constexpr size_t OFF_Y1   = OFF_Y0 + (size_t)NN*64*4;
// total ~59.6 MB

// ---------------- CSR build ----------------
__global__ void k_count(const int* __restrict__ dst, int* __restrict__ cnt) {
  int i = blockIdx.x * blockDim.x + threadIdx.x;
  int stride = gridDim.x * blockDim.x;
  for (; i < NE; i += stride) atomicAdd(&cnt[dst[i]], 1);
}

__global__ void k_scan1(const int* __restrict__ cnt, int* __restrict__ part) {
  __shared__ int sd[256];
  int t = threadIdx.x;
  int base = blockIdx.x * 1024 + t * 4;
  int s = 0;
#pragma unroll
  for (int i = 0; i < 4; i++) { int idx = base + i; if (idx < NN) s += cnt[idx]; }
  sd[t] = s; __syncthreads();
  for (int o = 128; o > 0; o >>= 1) { if (t < o) sd[t] += sd[t + o]; __syncthreads(); }
  if (t == 0) part[blockIdx.x] = sd[0];
}

__global__ void k_scan2(int* part, int nb, int* row_end) {
  __shared__ int sd[256];
  int t = threadIdx.x;
  int v = (t < nb) ? part[t] : 0;
  sd[t] = v; __syncthreads();
  for (int o = 1; o < 256; o <<= 1) {
    int x = (t >= o) ? sd[t - o] : 0;
    __syncthreads();
    sd[t] += x;
    __syncthreads();
  }
  if (t < nb) part[t] = sd[t] - v;       // exclusive block offsets
  if (t == nb - 1) *row_end = sd[t];     // row[NN] = total edges
}

__global__ void k_scan3(const int* __restrict__ cnt, const int* __restrict__ part,
                        int* __restrict__ row) {
  __shared__ int sd[256];
  int t = threadIdx.x;
  int base = blockIdx.x * 1024 + t * 4;
  int v[4]; int s = 0;
#pragma unroll
  for (int i = 0; i < 4; i++) { int idx = base + i; v[i] = (idx < NN) ? cnt[idx] : 0; s += v[i]; }
  int self = s;
  sd[t] = s; __syncthreads();
  for (int o = 1; o < 256; o <<= 1) {
    int x = (t >= o) ? sd[t - o] : 0;
    __syncthreads();
    sd[t] += x;
    __syncthreads();
  }
  int off = part[blockIdx.x] + (sd[t] - self);
#pragma unroll
  for (int i = 0; i < 4; i++) { int idx = base + i; if (idx < NN) row[idx] = off; off += v[i]; }
}

__global__ void k_fill(const int* __restrict__ src, const int* __restrict__ dst,
                       const int* __restrict__ row, int* __restrict__ cur,
                       int* __restrict__ csr) {
  int i = blockIdx.x * blockDim.x + threadIdx.x;
  int stride = gridDim.x * blockDim.x;
  for (; i < NE; i += stride) {
    int d = dst[i];
    int p = atomicAdd(&cur[d], 1);
    csr[row[d] + p] = src[i];
  }
}

// ---------------- y0 = x @ c1_w1  (K=128) ----------------
__global__ void __launch_bounds__(256) k_gemm_x(const float* __restrict__ x,
                                                const float* __restrict__ w,
                                                float* __restrict__ y) {
  __shared__ float lw[128 * 64];
  __shared__ float lx[4][128];
  int tid = threadIdx.x;
  for (int i = tid; i < 128 * 64 / 4; i += 256)
    ((float4*)lw)[i] = ((const float4*)w)[i];
  __syncthreads();
  int wid = tid >> 6, lane = tid & 63;
  for (int n0 = blockIdx.x * 4; n0 < NN; n0 += gridDim.x * 4) {
    int node = n0 + wid;
    bool valid = node < NN;
    if (valid) {
      lx[wid][lane]      = x[(size_t)node * 128 + lane];
      lx[wid][64 + lane] = x[(size_t)node * 128 + 64 + lane];
    }
    __syncthreads();
    if (valid) {
      float a0 = 0, a1 = 0, a2 = 0, a3 = 0;
      for (int k = 0; k < 128; k += 4) {
        a0 = fmaf(lx[wid][k + 0], lw[(k + 0) * 64 + lane], a0);
        a1 = fmaf(lx[wid][k + 1], lw[(k + 1) * 64 + lane], a1);
        a2 = fmaf(lx[wid][k + 2], lw[(k + 2) * 64 + lane], a2);
        a3 = fmaf(lx[wid][k + 3], lw[(k + 3) * 64 + lane], a3);
      }
      y[(size_t)node * 64 + lane] = (a0 + a1) + (a2 + a3);
    }
    __syncthreads();
  }
}

// ---------------- fused GIN layer ----------------
// in: y = h@w1 for this layer.  out: yout = h'@w1next
__global__ void __launch_bounds__(256) k_layer(
    const float* __restrict__ y, const int* __restrict__ row, const int* __restrict__ csr,
    const float* __restrict__ epsv, int ei,
    const float* __restrict__ b1, const float* __restrict__ w2, const float* __restrict__ b2,
    const float* __restrict__ gamma, const float* __restrict__ beta,
    const float* __restrict__ mean, const float* __restrict__ var,
    const float* __restrict__ wn, float* __restrict__ yout) {
  __shared__ float lw2[64 * 64];
  __shared__ float lwn[64 * 64];
  __shared__ float lu[4][64];
  int tid = threadIdx.x;
  for (int i = tid; i < 1024; i += 256) {
    ((float4*)lw2)[i] = ((const float4*)w2)[i];
    ((float4*)lwn)[i] = ((const float4*)wn)[i];
  }
  __syncthreads();
  int wid = tid >> 6, lane = tid & 63;
  float e1 = 1.0f + epsv[ei];
  float b1l = b1[lane], b2l = b2[lane];
  float gl = gamma[lane], bl = beta[lane], ml = mean[lane];
  float rvl = rsqrtf(var[lane] + BN_EPS);
  for (int n0 = blockIdx.x * 4; n0 < NN; n0 += gridDim.x * 4) {
    int node = n0 + wid;
    bool valid = node < NN;
    float u = 0.f;
    if (valid) {
      float agg = 0.f;
      int rs = row[node], re = row[node + 1];
      for (int i0 = rs; i0 < re; i0 += 64) {
        int c = re - i0; if (c > 64) c = 64;
        int sidx = (lane < c) ? csr[i0 + lane] : 0;
        for (int j = 0; j < c; j++) {
          int s = __shfl(sidx, j);
          agg += y[(size_t)s * 64 + lane];
        }
      }
      u = fmaxf(fmaf(e1, y[(size_t)node * 64 + lane], agg + b1l), 0.f);
    }
    lu[wid][lane] = u;
    __syncthreads();
    float a0 = 0, a1 = 0, a2 = 0, a3 = 0;
    for (int k = 0; k < 64; k += 4) {
      a0 = fmaf(lu[wid][k + 0], lw2[(k + 0) * 64 + lane], a0);
      a1 = fmaf(lu[wid][k + 1], lw2[(k + 1) * 64 + lane], a1);
      a2 = fmaf(lu[wid][k + 2], lw2[(k + 2) * 64 + lane], a2);
      a3 = fmaf(lu[wid][k + 3], lw2[(k + 3) * 64 + lane], a3);
    }
    float v = fmaxf((a0 + a1) + (a2 + a3) + b2l, 0.f);
    float hb = fmaf(gl * (v - ml), rvl, bl);   // eval-mode BN
    __syncthreads();
    lu[wid][lane] = hb;
    __syncthreads();
    float c0 = 0, c1 = 0, c2 = 0, c3 = 0;
    for (int k = 0; k < 64; k += 4) {
      c0 = fmaf(lu[wid][k + 0], lwn[(k + 0) * 64 + lane], c0);
      c1 = fmaf(lu[wid][k + 1], lwn[(k + 1) * 64 + lane], c1);
      c2 = fmaf(lu[wid][k + 2], lwn[(k + 2) * 64 + lane], c2);
      c3 = fmaf(lu[wid][k + 3], lwn[(k + 3) * 64 + lane], c3);
    }
    if (valid) yout[(size_t)node * 64 + lane] = (c0 + c1) + (c2 + c3);
    __syncthreads();
  }
}

// ---------------- final fused layer + head ----------------
__global__ void __launch_bounds__(256) k_layer_final(
    const float* __restrict__ y, const int* __restrict__ row, const int* __restrict__ csr,
    const float* __restrict__ epsv, int ei,
    const float* __restrict__ b1, const float* __restrict__ w2, const float* __restrict__ b2,
    const float* __restrict__ gamma, const float* __restrict__ beta,
    const float* __restrict__ mean, const float* __restrict__ var,
    const float* __restrict__ l1w, const float* __restrict__ l1b,
    const float* __restrict__ l2w, const float* __restrict__ l2b,
    float* __restrict__ out) {
  __shared__ float lw2[64 * 64];
  __shared__ float lh1[64 * 64];
  __shared__ float lh2[64 * 40];
  __shared__ float lu[4][64];
  int tid = threadIdx.x;
  for (int i = tid; i < 1024; i += 256) {
    ((float4*)lw2)[i] = ((const float4*)w2)[i];
    ((float4*)lh1)[i] = ((const float4*)l1w)[i];
  }
  for (int i = tid; i < 640; i += 256) ((float4*)lh2)[i] = ((const float4*)l2w)[i];
  __syncthreads();
  int wid = tid >> 6, lane = tid & 63;
  float e1 = 1.0f + epsv[ei];
  float b1l = b1[lane], b2l = b2[lane];
  float gl = gamma[lane], bl = beta[lane], ml = mean[lane];
  float rvl = rsqrtf(var[lane] + BN_EPS);
  float l1bl = l1b[lane];
  float l2bl = (lane < 40) ? l2b[lane] : 0.f;
  for (int n0 = blockIdx.x * 4; n0 < NN; n0 += gridDim.x * 4) {
    int node = n0 + wid;
    bool valid = node < NN;
    float u = 0.f;
    if (valid) {
      float agg = 0.f;
      int rs = row[node], re = row[node + 1];
      for (int i0 = rs; i0 < re; i0 += 64) {
        int c = re - i0; if (c > 64) c = 64;
        int sidx = (lane < c) ? csr[i0 + lane] : 0;
        for (int j = 0; j < c; j++) {
          int s = __shfl(sidx, j);
          agg += y[(size_t)s * 64 + lane];
        }
      }
      u = fmaxf(fmaf(e1, y[(size_t)node * 64 + lane], agg + b1l), 0.f);
    }
    lu[wid][lane] = u;
    __syncthreads();
    float a0 = 0, a1 = 0, a2 = 0, a3 = 0;
    for (int k = 0; k < 64; k += 4) {
      a0 = fmaf(lu[wid][k + 0], lw2[(k + 0) * 64 + lane], a0);
      a1 = fmaf(lu[wid][k + 1], lw2[(k + 1) * 64 + lane], a1);
      a2 = fmaf(lu[wid][k + 2], lw2[(k + 2) * 64 + lane], a2);
      a3 = fmaf(lu[wid][k + 3], lw2[(k + 3) * 64 + lane], a3);
    }
    float v = fmaxf((a0 + a1) + (a2 + a3) + b2l, 0.f);
    float hb = fmaf(gl * (v - ml), rvl, bl);
    __syncthreads();
    lu[wid][lane] = hb;
    __syncthreads();
    // f = relu(h @ lin1 + l1b)
    float c0 = 0, c1 = 0, c2 = 0, c3 = 0;
    for (int k = 0; k < 64; k += 4) {
      c0 = fmaf(lu[wid][k + 0], lh1[(k + 0) * 64 + lane], c0);
      c1 = fmaf(lu[wid][k + 1], lh1[(k + 1) * 64 + lane], c1);
      c2 = fmaf(lu[wid][k + 2], lh1[(k + 2) * 64 + lane], c2);
      c3 = fmaf(lu[wid][k + 3], lh1[(k + 3) * 64 + lane], c3);
    }
    float f = fmaxf((c0 + c1) + (c2 + c3) + l1bl, 0.f);
    __syncthreads();
    lu[wid][lane] = f;
    __syncthreads();
    if (valid && lane < 40) {
      float o0 = 0, o1 = 0, o2 = 0, o3 = 0;
      for (int k = 0; k < 64; k += 4) {
        o0 = fmaf(lu[wid][k + 0], lh2[(k + 0) * 40 + lane], o0);
        o1 = fmaf(lu[wid][k + 1], lh2[(k + 1) * 40 + lane], o1);
        o2 = fmaf(lu[wid][k + 2], lh2[(k + 2) * 40 + lane], o2);
        o3 = fmaf(lu[wid][k + 3], lh2[(k + 3) * 40 + lane], o3);
      }
      out[(size_t)node * 40 + lane] = (o0 + o1) + (o2 + o3) + l2bl;
    }
    __syncthreads();
  }
}

extern "C" void kernel_launch(void* const* d_in, const int* in_sizes, int n_in,
                              void* d_out, int out_size, void* d_ws, size_t ws_size,
                              hipStream_t stream) {
  const float* x   = (const float*)d_in[0];
  const int*   ei  = (const int*)d_in[1];
  const int*   src = ei;
  const int*   dst = ei + NE;
  const float* eps = (const float*)d_in[2];
  const float* c1_w1 = (const float*)d_in[3];
  const float* c1_b1 = (const float*)d_in[4];
  const float* c1_w2 = (const float*)d_in[5];
  const float* c1_b2 = (const float*)d_in[6];
  const float* c1_gamma = (const float*)d_in[7];
  const float* c1_beta  = (const float*)d_in[8];
  const float* c1_mean  = (const float*)d_in[9];
  const float* c1_var   = (const float*)d_in[10];
  const float* cw1 = (const float*)d_in[11];
  const float* cb1 = (const float*)d_in[12];
  const float* cw2 = (const float*)d_in[13];
  const float* cb2 = (const float*)d_in[14];
  const float* cgamma = (const float*)d_in[15];
  const float* cbeta  = (const float*)d_in[16];
  const float* cmean  = (const float*)d_in[17];
  const float* cvar   = (const float*)d_in[18];
  const float* lin1_w = (const float*)d_in[19];
  const float* lin1_b = (const float*)d_in[20];
  const float* lin2_w = (const float*)d_in[21];
  const float* lin2_b = (const float*)d_in[22];
  float* out = (float*)d_out;

  char* ws = (char*)d_ws;
  int* row  = (int*)(ws + OFF_ROW);
  int* cnt  = (int*)(ws + OFF_CNT);
  int* cur  = (int*)(ws + OFF_CUR);
  int* part = (int*)(ws + OFF_PART);
  int* csr  = (int*)(ws + OFF_CSR);
  float* y0 = (float*)(ws + OFF_Y0);
  float* y1 = (float*)(ws + OFF_Y1);

  hipMemsetAsync(cnt, 0, (size_t)NN * 4, stream);
  hipMemsetAsync(cur, 0, (size_t)NN * 4, stream);

  k_count<<<1024, 256, 0, stream>>>(dst, cnt);
  k_scan1<<<98, 256, 0, stream>>>(cnt, part);
  k_scan2<<<1, 256, 0, stream>>>(part, 98, row + NN);
  k_scan3<<<98, 256, 0, stream>>>(cnt, part, row);
  k_fill<<<1024, 256, 0, stream>>>(src, dst, row, cur, csr);

  // y0 = x @ c1_w1
  k_gemm_x<<<2048, 256, 0, stream>>>(x, c1_w1, y0);
  // layer 1 -> y1 = h1 @ cw1[0]
  k_layer<<<2048, 256, 0, stream>>>(y0, row, csr, eps, 0,
                                    c1_b1, c1_w2, c1_b2,
                                    c1_gamma, c1_beta, c1_mean, c1_var,
                                    cw1, y1);
  // layer 2 -> y0 = h2 @ cw1[1]
  k_layer<<<2048, 256, 0, stream>>>(y1, row, csr, eps, 1,
                                    cb1, cw2, cb2,
                                    cgamma, cbeta, cmean, cvar,
                                    cw1 + 64 * 64, y0);
  // layer 3 + head -> out
  k_layer_final<<<2048, 256, 0, stream>>>(y0, row, csr, eps, 2,
                                          cb1 + 64, cw2 + 64 * 64, cb2 + 64,
                                          cgamma + 64, cbeta + 64, cmean + 64, cvar + 64,
                                          lin1_w, lin1_b, lin2_w, lin2_b,
                                          out);
}

// Round 2
// 466.428 us; speedup vs baseline: 2.3468x; 2.3468x over previous
//
#include <hip/hip_runtime.h>

#define NN 100000
#define NE 1600000
#define BN_EPS 1e-5f

typedef unsigned int u32;
typedef unsigned short u16;

// ---- workspace layout (bytes) ----
static constexpr size_t OFF_ROW  = 0;              // (NN+1) ints
static constexpr size_t OFF_CNT  = 512u*1024;      // NN ints
static constexpr size_t OFF_CUR  = 1024u*1024;     // NN ints
static constexpr size_t OFF_PART = 1536u*1024;     // 256 ints
static constexpr size_t OFF_CSR  = 1600u*1024;     // NE ints (ends at 8.0 MB)
static constexpr size_t OFF_U    = 8u*1024*1024;                 // NN*64 f32 (25.6 MB)
static constexpr size_t OFF_YB0  = OFF_U + (size_t)NN*64*4;      // NN*64 bf16 (12.8 MB)
static constexpr size_t OFF_YB1  = OFF_YB0 + (size_t)NN*64*2;    // NN*64 bf16
// end = 59,588,608 bytes — same footprint as round 1

__device__ __forceinline__ u16 f2bf(float f) {
  u32 u = __float_as_uint(f);
  return (u16)((u + 0x7fffu + ((u >> 16) & 1u)) >> 16);
}
__device__ __forceinline__ float bflo(u32 u) { return __uint_as_float(u << 16); }
__device__ __forceinline__ float bfhi(u32 u) { return __uint_as_float(u & 0xffff0000u); }
__device__ __forceinline__ u32 pkbf(float lo, float hi) {
  return (u32)f2bf(lo) | ((u32)f2bf(hi) << 16);
}

// ---------------- CSR build (unchanged) ----------------
__global__ void k_count(const int* __restrict__ dst, int* __restrict__ cnt) {
  int i = blockIdx.x * blockDim.x + threadIdx.x;
  int stride = gridDim.x * blockDim.x;
  for (; i < NE; i += stride) atomicAdd(&cnt[dst[i]], 1);
}

__global__ void k_scan1(const int* __restrict__ cnt, int* __restrict__ part) {
  __shared__ int sd[256];
  int t = threadIdx.x;
  int base = blockIdx.x * 1024 + t * 4;
  int s = 0;
#pragma unroll
  for (int i = 0; i < 4; i++) { int idx = base + i; if (idx < NN) s += cnt[idx]; }
  sd[t] = s; __syncthreads();
  for (int o = 128; o > 0; o >>= 1) { if (t < o) sd[t] += sd[t + o]; __syncthreads(); }
  if (t == 0) part[blockIdx.x] = sd[0];
}

__global__ void k_scan2(int* part, int nb, int* row_end) {
  __shared__ int sd[256];
  int t = threadIdx.x;
  int v = (t < nb) ? part[t] : 0;
  sd[t] = v; __syncthreads();
  for (int o = 1; o < 256; o <<= 1) {
    int x = (t >= o) ? sd[t - o] : 0;
    __syncthreads();
    sd[t] += x;
    __syncthreads();
  }
  if (t < nb) part[t] = sd[t] - v;
  if (t == nb - 1) *row_end = sd[t];
}

__global__ void k_scan3(const int* __restrict__ cnt, const int* __restrict__ part,
                        int* __restrict__ row) {
  __shared__ int sd[256];
  int t = threadIdx.x;
  int base = blockIdx.x * 1024 + t * 4;
  int v[4]; int s = 0;
#pragma unroll
  for (int i = 0; i < 4; i++) { int idx = base + i; v[i] = (idx < NN) ? cnt[idx] : 0; s += v[i]; }
  int self = s;
  sd[t] = s; __syncthreads();
  for (int o = 1; o < 256; o <<= 1) {
    int x = (t >= o) ? sd[t - o] : 0;
    __syncthreads();
    sd[t] += x;
    __syncthreads();
  }
  int off = part[blockIdx.x] + (sd[t] - self);
#pragma unroll
  for (int i = 0; i < 4; i++) { int idx = base + i; if (idx < NN) row[idx] = off; off += v[i]; }
}

__global__ void k_fill(const int* __restrict__ src, const int* __restrict__ dst,
                       const int* __restrict__ row, int* __restrict__ cur,
                       int* __restrict__ csr) {
  int i = blockIdx.x * blockDim.x + threadIdx.x;
  int stride = gridDim.x * blockDim.x;
  for (; i < NE; i += stride) {
    int d = dst[i];
    int p = atomicAdd(&cur[d], 1);
    csr[row[d] + p] = src[i];
  }
}

// ---------------- yb0 = bf16(x @ c1_w1)  (K=128) ----------------
__global__ void __launch_bounds__(256) k_gemm_x(const float* __restrict__ x,
                                                const float* __restrict__ w,
                                                u16* __restrict__ yb) {
  __shared__ float lw[128 * 64];
  __shared__ float lx[4][128];
  int tid = threadIdx.x;
  for (int i = tid; i < 128 * 64 / 4; i += 256)
    ((float4*)lw)[i] = ((const float4*)w)[i];
  __syncthreads();
  int wid = tid >> 6, lane = tid & 63;
  for (int n0 = blockIdx.x * 4; n0 < NN; n0 += gridDim.x * 4) {
    int node = n0 + wid;
    bool valid = node < NN;
    if (valid) {
      lx[wid][lane]      = x[(size_t)node * 128 + lane];
      lx[wid][64 + lane] = x[(size_t)node * 128 + 64 + lane];
    }
    __syncthreads();
    if (valid) {
      float a0 = 0, a1 = 0, a2 = 0, a3 = 0;
      for (int k = 0; k < 128; k += 4) {
        a0 = fmaf(lx[wid][k + 0], lw[(k + 0) * 64 + lane], a0);
        a1 = fmaf(lx[wid][k + 1], lw[(k + 1) * 64 + lane], a1);
        a2 = fmaf(lx[wid][k + 2], lw[(k + 2) * 64 + lane], a2);
        a3 = fmaf(lx[wid][k + 3], lw[(k + 3) * 64 + lane], a3);
      }
      yb[(size_t)node * 64 + lane] = f2bf((a0 + a1) + (a2 + a3));
    }
    __syncthreads();
  }
}

// ---------------- aggregation: u = relu((1+eps)*y + sum_nbr y + b1) ----------------
// thread = (node, feature-octet). bf16 gather rows (128 B), fp32 accumulate.
__global__ void __launch_bounds__(256) k_agg(
    const u16* __restrict__ yb, const int* __restrict__ row, const int* __restrict__ csr,
    const float* __restrict__ epsv, int ei, const float* __restrict__ b1,
    float* __restrict__ u) {
  int t = blockIdx.x * 256 + threadIdx.x;
  int n = t >> 3, g = t & 7;
  if (n >= NN) return;
  const u16* bp = yb + g * 8;
  float a0 = 0, a1 = 0, a2 = 0, a3 = 0, a4 = 0, a5 = 0, a6 = 0, a7 = 0;
  int rs = row[n], re = row[n + 1];
  int i = rs;
  for (; i + 4 <= re; i += 4) {
    int s0 = csr[i], s1 = csr[i + 1], s2 = csr[i + 2], s3 = csr[i + 3];
    uint4 v0 = *(const uint4*)(bp + (size_t)s0 * 64);
    uint4 v1 = *(const uint4*)(bp + (size_t)s1 * 64);
    uint4 v2 = *(const uint4*)(bp + (size_t)s2 * 64);
    uint4 v3 = *(const uint4*)(bp + (size_t)s3 * 64);
    a0 += bflo(v0.x); a1 += bfhi(v0.x); a2 += bflo(v0.y); a3 += bfhi(v0.y);
    a4 += bflo(v0.z); a5 += bfhi(v0.z); a6 += bflo(v0.w); a7 += bfhi(v0.w);
    a0 += bflo(v1.x); a1 += bfhi(v1.x); a2 += bflo(v1.y); a3 += bfhi(v1.y);
    a4 += bflo(v1.z); a5 += bfhi(v1.z); a6 += bflo(v1.w); a7 += bfhi(v1.w);
    a0 += bflo(v2.x); a1 += bfhi(v2.x); a2 += bflo(v2.y); a3 += bfhi(v2.y);
    a4 += bflo(v2.z); a5 += bfhi(v2.z); a6 += bflo(v2.w); a7 += bfhi(v2.w);
    a0 += bflo(v3.x); a1 += bfhi(v3.x); a2 += bflo(v3.y); a3 += bfhi(v3.y);
    a4 += bflo(v3.z); a5 += bfhi(v3.z); a6 += bflo(v3.w); a7 += bfhi(v3.w);
  }
  for (; i < re; ++i) {
    int s0 = csr[i];
    uint4 v0 = *(const uint4*)(bp + (size_t)s0 * 64);
    a0 += bflo(v0.x); a1 += bfhi(v0.x); a2 += bflo(v0.y); a3 += bfhi(v0.y);
    a4 += bflo(v0.z); a5 += bfhi(v0.z); a6 += bflo(v0.w); a7 += bfhi(v0.w);
  }
  uint4 sv = *(const uint4*)(bp + (size_t)n * 64);
  float e1 = 1.0f + epsv[ei];
  const float* bb = b1 + g * 8;
  float r0 = fmaxf(fmaf(e1, bflo(sv.x), a0 + bb[0]), 0.f);
  float r1 = fmaxf(fmaf(e1, bfhi(sv.x), a1 + bb[1]), 0.f);
  float r2 = fmaxf(fmaf(e1, bflo(sv.y), a2 + bb[2]), 0.f);
  float r3 = fmaxf(fmaf(e1, bfhi(sv.y), a3 + bb[3]), 0.f);
  float r4 = fmaxf(fmaf(e1, bflo(sv.z), a4 + bb[4]), 0.f);
  float r5 = fmaxf(fmaf(e1, bfhi(sv.z), a5 + bb[5]), 0.f);
  float r6 = fmaxf(fmaf(e1, bflo(sv.w), a6 + bb[6]), 0.f);
  float r7 = fmaxf(fmaf(e1, bfhi(sv.w), a7 + bb[7]), 0.f);
  float4* up = (float4*)(u + (size_t)n * 64 + g * 8);
  up[0] = make_float4(r0, r1, r2, r3);
  up[1] = make_float4(r4, r5, r6, r7);
}

// ---------------- MLP: yout = bf16( BN(relu(u@w2+b2)) @ wn ) ----------------
// wave = 32-node tile; lane = (ng=lane>>3 -> 4 nodes, jg=lane&7 -> 8 feats)
__global__ void __launch_bounds__(256) k_mlp(
    const float* __restrict__ u, const float* __restrict__ w2, const float* __restrict__ b2,
    const float* __restrict__ gamma, const float* __restrict__ beta,
    const float* __restrict__ mean, const float* __restrict__ var,
    const float* __restrict__ wn, u16* __restrict__ yout) {
  __shared__ float lw2[64 * 64];
  __shared__ float lwn[64 * 64];
  __shared__ float ut[4][32][68];
  int tid = threadIdx.x;
  for (int idx = tid; idx < 1024; idx += 256) {
    ((float4*)lw2)[idx] = ((const float4*)w2)[idx];
    ((float4*)lwn)[idx] = ((const float4*)wn)[idx];
  }
  __syncthreads();
  int wid = tid >> 6, lane = tid & 63;
  int ng = lane >> 3, jg = lane & 7;
  int jb = jg * 8;
  int tile = blockIdx.x * 4 + wid;
  if (tile >= NN / 32) return;   // NN%32==0, wave-uniform
  float gl[8], be[8], mn[8], rv[8], bb[8];
#pragma unroll
  for (int jj = 0; jj < 8; jj++) {
    int j = jb + jj;
    gl[jj] = gamma[j]; be[jj] = beta[j]; mn[jj] = mean[j];
    rv[jj] = rsqrtf(var[j] + BN_EPS); bb[jj] = b2[j];
  }
  int n0 = tile * 32;
  int r4 = lane >> 4;
  int k0 = (lane & 15) * 4;
  const float* ug = u + (size_t)n0 * 64;
#pragma unroll
  for (int p = 0; p < 8; p++) {
    float4 val = *(const float4*)(ug + (size_t)(p * 4 + r4) * 64 + k0);
    *(float4*)&ut[wid][p * 4 + r4][k0] = val;
  }
  float acc[4][8];
#pragma unroll
  for (int c = 0; c < 4; c++)
#pragma unroll
    for (int jj = 0; jj < 8; jj++) acc[c][jj] = 0.f;
#pragma unroll 4
  for (int k = 0; k < 64; k++) {
    float4 wA = *(const float4*)&lw2[k * 64 + jb];
    float4 wB = *(const float4*)&lw2[k * 64 + jb + 4];
    float uv[4];
#pragma unroll
    for (int c = 0; c < 4; c++) uv[c] = ut[wid][ng * 4 + c][k];
#pragma unroll
    for (int c = 0; c < 4; c++) {
      acc[c][0] = fmaf(uv[c], wA.x, acc[c][0]);
      acc[c][1] = fmaf(uv[c], wA.y, acc[c][1]);
      acc[c][2] = fmaf(uv[c], wA.z, acc[c][2]);
      acc[c][3] = fmaf(uv[c], wA.w, acc[c][3]);
      acc[c][4] = fmaf(uv[c], wB.x, acc[c][4]);
      acc[c][5] = fmaf(uv[c], wB.y, acc[c][5]);
      acc[c][6] = fmaf(uv[c], wB.z, acc[c][6]);
      acc[c][7] = fmaf(uv[c], wB.w, acc[c][7]);
    }
  }
  // relu + bias + BN, store hb back to ut (lockstep wave => reads already done)
#pragma unroll
  for (int c = 0; c < 4; c++) {
    float h[8];
#pragma unroll
    for (int jj = 0; jj < 8; jj++) {
      float v = fmaxf(acc[c][jj] + bb[jj], 0.f);
      h[jj] = fmaf(gl[jj] * (v - mn[jj]), rv[jj], be[jj]);
    }
    *(float4*)&ut[wid][ng * 4 + c][jb]     = make_float4(h[0], h[1], h[2], h[3]);
    *(float4*)&ut[wid][ng * 4 + c][jb + 4] = make_float4(h[4], h[5], h[6], h[7]);
  }
  float ac2[4][8];
#pragma unroll
  for (int c = 0; c < 4; c++)
#pragma unroll
    for (int jj = 0; jj < 8; jj++) ac2[c][jj] = 0.f;
#pragma unroll 4
  for (int k = 0; k < 64; k++) {
    float4 wA = *(const float4*)&lwn[k * 64 + jb];
    float4 wB = *(const float4*)&lwn[k * 64 + jb + 4];
    float uv[4];
#pragma unroll
    for (int c = 0; c < 4; c++) uv[c] = ut[wid][ng * 4 + c][k];
#pragma unroll
    for (int c = 0; c < 4; c++) {
      ac2[c][0] = fmaf(uv[c], wA.x, ac2[c][0]);
      ac2[c][1] = fmaf(uv[c], wA.y, ac2[c][1]);
      ac2[c][2] = fmaf(uv[c], wA.z, ac2[c][2]);
      ac2[c][3] = fmaf(uv[c], wA.w, ac2[c][3]);
      ac2[c][4] = fmaf(uv[c], wB.x, ac2[c][4]);
      ac2[c][5] = fmaf(uv[c], wB.y, ac2[c][5]);
      ac2[c][6] = fmaf(uv[c], wB.z, ac2[c][6]);
      ac2[c][7] = fmaf(uv[c], wB.w, ac2[c][7]);
    }
  }
#pragma unroll
  for (int c = 0; c < 4; c++) {
    int n = n0 + ng * 4 + c;
    uint4 pk;
    pk.x = pkbf(ac2[c][0], ac2[c][1]);
    pk.y = pkbf(ac2[c][2], ac2[c][3]);
    pk.z = pkbf(ac2[c][4], ac2[c][5]);
    pk.w = pkbf(ac2[c][6], ac2[c][7]);
    *(uint4*)(yout + (size_t)n * 64 + jb) = pk;
  }
}

// ---------------- final MLP + head: out = (relu(BN(relu(u@w2+b2))@l1w+l1b)) @ l2w + l2b ----------------
__global__ void __launch_bounds__(256) k_mlp_final(
    const float* __restrict__ u, const float* __restrict__ w2, const float* __restrict__ b2,
    const float* __restrict__ gamma, const float* __restrict__ beta,
    const float* __restrict__ mean, const float* __restrict__ var,
    const float* __restrict__ l1w, const float* __restrict__ l1b,
    const float* __restrict__ l2w, const float* __restrict__ l2b,
    float* __restrict__ out) {
  __shared__ float lw2[64 * 64];
  __shared__ float lh1[64 * 64];
  __shared__ float lh2[64 * 40];
  __shared__ float ut[4][32][68];
  int tid = threadIdx.x;
  for (int idx = tid; idx < 1024; idx += 256) {
    ((float4*)lw2)[idx] = ((const float4*)w2)[idx];
    ((float4*)lh1)[idx] = ((const float4*)l1w)[idx];
  }
  for (int idx = tid; idx < 640; idx += 256) ((float4*)lh2)[idx] = ((const float4*)l2w)[idx];
  __syncthreads();
  int wid = tid >> 6, lane = tid & 63;
  int ng = lane >> 3, jg = lane & 7;
  int jb = jg * 8;
  int tile = blockIdx.x * 4 + wid;
  if (tile >= NN / 32) return;
  float gl[8], be[8], mn[8], rv[8], bb[8], lb[8];
#pragma unroll
  for (int jj = 0; jj < 8; jj++) {
    int j = jb + jj;
    gl[jj] = gamma[j]; be[jj] = beta[j]; mn[jj] = mean[j];
    rv[jj] = rsqrtf(var[j] + BN_EPS); bb[jj] = b2[j]; lb[jj] = l1b[j];
  }
  float l2bv[5];
#pragma unroll
  for (int jj = 0; jj < 5; jj++) l2bv[jj] = l2b[jg * 5 + jj];
  int n0 = tile * 32;
  int r4 = lane >> 4;
  int k0 = (lane & 15) * 4;
  const float* ug = u + (size_t)n0 * 64;
#pragma unroll
  for (int p = 0; p < 8; p++) {
    float4 val = *(const float4*)(ug + (size_t)(p * 4 + r4) * 64 + k0);
    *(float4*)&ut[wid][p * 4 + r4][k0] = val;
  }
  float acc[4][8];
#pragma unroll
  for (int c = 0; c < 4; c++)
#pragma unroll
    for (int jj = 0; jj < 8; jj++) acc[c][jj] = 0.f;
#pragma unroll 4
  for (int k = 0; k < 64; k++) {
    float4 wA = *(const float4*)&lw2[k * 64 + jb];
    float4 wB = *(const float4*)&lw2[k * 64 + jb + 4];
    float uv[4];
#pragma unroll
    for (int c = 0; c < 4; c++) uv[c] = ut[wid][ng * 4 + c][k];
#pragma unroll
    for (int c = 0; c < 4; c++) {
      acc[c][0] = fmaf(uv[c], wA.x, acc[c][0]);
      acc[c][1] = fmaf(uv[c], wA.y, acc[c][1]);
      acc[c][2] = fmaf(uv[c], wA.z, acc[c][2]);
      acc[c][3] = fmaf(uv[c], wA.w, acc[c][3]);
      acc[c][4] = fmaf(uv[c], wB.x, acc[c][4]);
      acc[c][5] = fmaf(uv[c], wB.y, acc[c][5]);
      acc[c][6] = fmaf(uv[c], wB.z, acc[c][6]);
      acc[c][7] = fmaf(uv[c], wB.w, acc[c][7]);
    }
  }
#pragma unroll
  for (int c = 0; c < 4; c++) {
    float h[8];
#pragma unroll
    for (int jj = 0; jj < 8; jj++) {
      float v = fmaxf(acc[c][jj] + bb[jj], 0.f);
      h[jj] = fmaf(gl[jj] * (v - mn[jj]), rv[jj], be[jj]);
    }
    *(float4*)&ut[wid][ng * 4 + c][jb]     = make_float4(h[0], h[1], h[2], h[3]);
    *(float4*)&ut[wid][ng * 4 + c][jb + 4] = make_float4(h[4], h[5], h[6], h[7]);
  }
  float ac2[4][8];
#pragma unroll
  for (int c = 0; c < 4; c++)
#pragma unroll
    for (int jj = 0; jj < 8; jj++) ac2[c][jj] = 0.f;
#pragma unroll 4
  for (int k = 0; k < 64; k++) {
    float4 wA = *(const float4*)&lh1[k * 64 + jb];
    float4 wB = *(const float4*)&lh1[k * 64 + jb + 4];
    float uv[4];
#pragma unroll
    for (int c = 0; c < 4; c++) uv[c] = ut[wid][ng * 4 + c][k];
#pragma unroll
    for (int c = 0; c < 4; c++) {
      ac2[c][0] = fmaf(uv[c], wA.x, ac2[c][0]);
      ac2[c][1] = fmaf(uv[c], wA.y, ac2[c][1]);
      ac2[c][2] = fmaf(uv[c], wA.z, ac2[c][2]);
      ac2[c][3] = fmaf(uv[c], wA.w, ac2[c][3]);
      ac2[c][4] = fmaf(uv[c], wB.x, ac2[c][4]);
      ac2[c][5] = fmaf(uv[c], wB.y, ac2[c][5]);
      ac2[c][6] = fmaf(uv[c], wB.z, ac2[c][6]);
      ac2[c][7] = fmaf(uv[c], wB.w, ac2[c][7]);
    }
  }
#pragma unroll
  for (int c = 0; c < 4; c++) {
    float f0 = fmaxf(ac2[c][0] + lb[0], 0.f), f1 = fmaxf(ac2[c][1] + lb[1], 0.f);
    float f2 = fmaxf(ac2[c][2] + lb[2], 0.f), f3 = fmaxf(ac2[c][3] + lb[3], 0.f);
    float f4 = fmaxf(ac2[c][4] + lb[4], 0.f), f5 = fmaxf(ac2[c][5] + lb[5], 0.f);
    float f6 = fmaxf(ac2[c][6] + lb[6], 0.f), f7 = fmaxf(ac2[c][7] + lb[7], 0.f);
    *(float4*)&ut[wid][ng * 4 + c][jb]     = make_float4(f0, f1, f2, f3);
    *(float4*)&ut[wid][ng * 4 + c][jb + 4] = make_float4(f4, f5, f6, f7);
  }
  float ac3[4][5];
#pragma unroll
  for (int c = 0; c < 4; c++)
#pragma unroll
    for (int jj = 0; jj < 5; jj++) ac3[c][jj] = 0.f;
#pragma unroll 4
  for (int k = 0; k < 64; k++) {
    float wv[5];
#pragma unroll
    for (int jj = 0; jj < 5; jj++) wv[jj] = lh2[k * 40 + jg * 5 + jj];
    float uv[4];
#pragma unroll
    for (int c = 0; c < 4; c++) uv[c] = ut[wid][ng * 4 + c][k];
#pragma unroll
    for (int c = 0; c < 4; c++)
#pragma unroll
      for (int jj = 0; jj < 5; jj++) ac3[c][jj] = fmaf(uv[c], wv[jj], ac3[c][jj]);
  }
#pragma unroll
  for (int c = 0; c < 4; c++) {
    int n = n0 + ng * 4 + c;
#pragma unroll
    for (int jj = 0; jj < 5; jj++)
      out[(size_t)n * 40 + jg * 5 + jj] = ac3[c][jj] + l2bv[jj];
  }
}

extern "C" void kernel_launch(void* const* d_in, const int* in_sizes, int n_in,
                              void* d_out, int out_size, void* d_ws, size_t ws_size,
                              hipStream_t stream) {
  const float* x   = (const float*)d_in[0];
  const int*   ei  = (const int*)d_in[1];
  const int*   src = ei;
  const int*   dst = ei + NE;
  const float* eps = (const float*)d_in[2];
  const float* c1_w1 = (const float*)d_in[3];
  const float* c1_b1 = (const float*)d_in[4];
  const float* c1_w2 = (const float*)d_in[5];
  const float* c1_b2 = (const float*)d_in[6];
  const float* c1_gamma = (const float*)d_in[7];
  const float* c1_beta  = (const float*)d_in[8];
  const float* c1_mean  = (const float*)d_in[9];
  const float* c1_var   = (const float*)d_in[10];
  const float* cw1 = (const float*)d_in[11];
  const float* cb1 = (const float*)d_in[12];
  const float* cw2 = (const float*)d_in[13];
  const float* cb2 = (const float*)d_in[14];
  const float* cgamma = (const float*)d_in[15];
  const float* cbeta  = (const float*)d_in[16];
  const float* cmean  = (const float*)d_in[17];
  const float* cvar   = (const float*)d_in[18];
  const float* lin1_w = (const float*)d_in[19];
  const float* lin1_b = (const float*)d_in[20];
  const float* lin2_w = (const float*)d_in[21];
  const float* lin2_b = (const float*)d_in[22];
  float* out = (float*)d_out;

  char* ws = (char*)d_ws;
  int* row  = (int*)(ws + OFF_ROW);
  int* cnt  = (int*)(ws + OFF_CNT);
  int* cur  = (int*)(ws + OFF_CUR);
  int* part = (int*)(ws + OFF_PART);
  int* csr  = (int*)(ws + OFF_CSR);
  float* u  = (float*)(ws + OFF_U);
  u16* yb0  = (u16*)(ws + OFF_YB0);
  u16* yb1  = (u16*)(ws + OFF_YB1);

  hipMemsetAsync(cnt, 0, (size_t)NN * 4, stream);
  hipMemsetAsync(cur, 0, (size_t)NN * 4, stream);

  k_count<<<1024, 256, 0, stream>>>(dst, cnt);
  k_scan1<<<98, 256, 0, stream>>>(cnt, part);
  k_scan2<<<1, 256, 0, stream>>>(part, 98, row + NN);
  k_scan3<<<98, 256, 0, stream>>>(cnt, part, row);
  k_fill<<<1024, 256, 0, stream>>>(src, dst, row, cur, csr);

  const int AGG_GRID = (NN * 8) / 256;          // 3125, exact
  const int MLP_GRID = (NN / 32 + 3) / 4;       // 782

  // y0 = bf16(x @ c1_w1)
  k_gemm_x<<<2048, 256, 0, stream>>>(x, c1_w1, yb0);

  // layer 1
  k_agg<<<AGG_GRID, 256, 0, stream>>>(yb0, row, csr, eps, 0, c1_b1, u);
  k_mlp<<<MLP_GRID, 256, 0, stream>>>(u, c1_w2, c1_b2,
                                      c1_gamma, c1_beta, c1_mean, c1_var,
                                      cw1, yb1);
  // layer 2
  k_agg<<<AGG_GRID, 256, 0, stream>>>(yb1, row, csr, eps, 1, cb1, u);
  k_mlp<<<MLP_GRID, 256, 0, stream>>>(u, cw2, cb2,
                                      cgamma, cbeta, cmean, cvar,
                                      cw1 + 64 * 64, yb0);
  // layer 3 + head
  k_agg<<<AGG_GRID, 256, 0, stream>>>(yb0, row, csr, eps, 2, cb1 + 64, u);
  k_mlp_final<<<MLP_GRID, 256, 0, stream>>>(u, cw2 + 64 * 64, cb2 + 64,
                                            cgamma + 64, cbeta + 64, cmean + 64, cvar + 64,
                                            lin1_w, lin1_b, lin2_w, lin2_b,
                                            out);
}